// Round 2
// baseline (531.990 us; speedup 1.0000x reference)
//
#include <hip/hip_runtime.h>

#define NBINS  16
#define TPB    256
#define BLOCKS 1024        // 4 blocks/CU co-resident (35KB LDS x 4 = 140KB < 160KB)
#define DUMMY  16          // dead-slot redirect row (17th plane row, never read)
#define MAGIC  12582912.0f // 1.5 * 2^23: float->int round-to-nearest-even trick

// d_ws layout: partial[cell * BLOCKS + blockIdx]; cells 0..15 cnt, 16..31 sum,
// 32..47 sumsq, 48 = sum (wq-w)^2.  49*1024 floats ~= 200 KB.
//
// R1 -> R2: LDS batching/dedup changed nothing (160->166us) => bottleneck is a
// MEMORY CONVOY: conditional 1-deep prefetch made the compiler guard loads
// behind a branch and drain vmcnt(0) before each iteration, so all 4
// waves/SIMD stall on HBM/L3 latency simultaneously (VALUBusy 35%, HBM 20%).
// Fix: exact per-thread trip count, straight-line UNCONDITIONAL loads, manual
// 2x unroll with named registers, prefetch distance 2 (loads issued one full
// round (~1000 cyc of issue work) before consumption -> vmcnt(N) waits).
// Also: magic-number bin extraction (fma+add+and replaces mul/rndne/cvt/add).

__global__ __launch_bounds__(TPB, 4) void binreg_main(
    const float* __restrict__ w, const float* __restrict__ wq,
    const float* __restrict__ alpha_p, const int* __restrict__ nbit_p,
    float* __restrict__ partial, long long n)
{
    __shared__ float2 sv_pl[(NBINS + 1) * TPB];  // {sum, sumsq}, +dummy row, 34.8 KB
    __shared__ float  cred[NBINS][TPB / 64];
    __shared__ float  sqpart[TPB / 64];

    const int tid = threadIdx.x;

    #pragma unroll
    for (int k = 0; k < NBINS; ++k)
        sv_pl[k * TPB + tid] = make_float2(0.0f, 0.0f);
    // columns are thread-private until the epilogue fold; no barrier needed

    const float inv_a = 1.0f / alpha_p[0];
    const int   qoff  = 1 << (nbit_p[0] - 1);   // -Qn = 8 for nbit=4

    const long long n4     = n >> 2;
    const long long stride = (long long)BLOCKS * TPB;   // compile-time 262144
    const float4* w4 = (const float4*)w;
    const float4* q4 = (const float4*)wq;

    float sq = 0.0f;
    unsigned long long clo = 0ull, chi = 0ull;   // 16 x 8-bit packed bin counters
    float cf[NBINS];
    #pragma unroll
    for (int k = 0; k < NBINS; ++k) cf[k] = 0.0f;
    int pend = 0;

    // one float4-pair worth of work; mutates sq/clo/chi/sv_pl
    auto process = [&](float4 a, float4 b) {
        float d0 = b.x - a.x, d1 = b.y - a.y, d2 = b.z - a.z, d3 = b.w - a.w;
        sq += d0 * d0 + d1 * d1 + d2 * d2 + d3 * d3;

        // bin = (rint(b*inv_a) + qoff) & 15 via magic-number float->int:
        // asint(fma(x, inv_a, 1.5*2^23)) == 0x4B400000 + rint(x*inv_a), and
        // 0x4B400000 % 16 == 0, so the mask sees the same value as before.
        const int b0 = (__float_as_int(fmaf(b.x, inv_a, MAGIC)) + qoff) & (NBINS - 1);
        const int b1 = (__float_as_int(fmaf(b.y, inv_a, MAGIC)) + qoff) & (NBINS - 1);
        const int b2 = (__float_as_int(fmaf(b.z, inv_a, MAGIC)) + qoff) & (NBINS - 1);
        const int b3 = (__float_as_int(fmaf(b.w, inv_a, MAGIC)) + qoff) & (NBINS - 1);

        // packed register counts (exact)
        {
            unsigned long long t;
            t = 1ull << ((b0 & 7) << 3); clo += (b0 < 8) ? t : 0ull; chi += (b0 < 8) ? 0ull : t;
            t = 1ull << ((b1 & 7) << 3); clo += (b1 < 8) ? t : 0ull; chi += (b1 < 8) ? 0ull : t;
            t = 1ull << ((b2 & 7) << 3); clo += (b2 < 8) ? t : 0ull; chi += (b2 < 8) ? 0ull : t;
            t = 1ull << ((b3 & 7) << 3); clo += (b3 < 8) ? t : 0ull; chi += (b3 < 8) ? 0ull : t;
        }

        // dedup: merge duplicate bins into the first (live) slot.
        const bool e10 = (b1 == b0);
        const bool e20 = (b2 == b0);
        const bool e21 = (b2 == b1) && !e20;
        const bool e30 = (b3 == b0);
        const bool e31 = (b3 == b1) && !e30;
        const bool e32 = (b3 == b2) && !e30 && !e31;

        float sx0 = a.x, sx1 = a.y, sx2 = a.z, sx3 = a.w;
        float qx0 = a.x * a.x, qx1 = a.y * a.y, qx2 = a.z * a.z, qx3 = a.w * a.w;

        sx0 += e10 ? sx1 : 0.0f;  qx0 += e10 ? qx1 : 0.0f;
        sx0 += e20 ? sx2 : 0.0f;  qx0 += e20 ? qx2 : 0.0f;
        sx1 += e21 ? sx2 : 0.0f;  qx1 += e21 ? qx2 : 0.0f;
        sx0 += e30 ? sx3 : 0.0f;  qx0 += e30 ? qx3 : 0.0f;
        sx1 += e31 ? sx3 : 0.0f;  qx1 += e31 ? qx3 : 0.0f;
        sx2 += e32 ? sx3 : 0.0f;  qx2 += e32 ? qx3 : 0.0f;

        const int r1 = e10               ? DUMMY : b1;
        const int r2 = (e20 | e21)       ? DUMMY : b2;
        const int r3 = (e30 | e31 | e32) ? DUMMY : b3;
        const int a0 = (b0 << 8) + tid;
        const int a1 = (r1 << 8) + tid;
        const int a2 = (r2 << 8) + tid;
        const int a3 = (r3 << 8) + tid;

        // batched reads (distinct live addresses) -> ONE lgkmcnt wait
        float2 t0 = sv_pl[a0];
        float2 t1 = sv_pl[a1];
        float2 t2 = sv_pl[a2];
        float2 t3 = sv_pl[a3];
        t0.x += sx0; t0.y += qx0;
        t1.x += sx1; t1.y += qx1;
        t2.x += sx2; t2.y += qx2;
        t3.x += sx3; t3.y += qx3;
        sv_pl[a0] = t0;
        sv_pl[a1] = t1;
        sv_pl[a2] = t2;
        sv_pl[a3] = t3;
    };

    const long long start = (long long)blockIdx.x * TPB + tid;
    long long cnt = 0;
    if (start < n4) cnt = 1 + (n4 - 1 - start) / stride;

    const float4* pw = w4 + start;
    const float4* pq = q4 + start;

    float4 aw0, aq0, aw1, aq1;
    if (cnt >= 1) { aw0 = pw[0];      aq0 = pq[0]; }
    if (cnt >= 2) { aw1 = pw[stride]; aq1 = pq[stride]; }

    long long k = 0;
    while (k + 3 < cnt) {
        // unconditional 2-deep prefetch: consumed NEXT round -> vmcnt slack of
        // one full round (~2 process() bodies) covers HBM/L3 latency.
        float4 nw0 = pw[2 * stride], nq0 = pq[2 * stride];
        process(aw0, aq0);
        float4 nw1 = pw[3 * stride], nq1 = pq[3 * stride];
        process(aw1, aq1);
        aw0 = nw0; aq0 = nq0; aw1 = nw1; aq1 = nq1;
        pw += 2 * stride; pq += 2 * stride;
        k += 2;

        // flush packed counters before any 8-bit field can overflow:
        // <=8 increments/field/round, flush every 16 rounds -> <=128 < 255
        if (++pend >= 16) {
            #pragma unroll
            for (int kk = 0; kk < 8; ++kk) {
                cf[kk]     += (float)((clo >> (kk * 8)) & 0xffull);
                cf[kk + 8] += (float)((chi >> (kk * 8)) & 0xffull);
            }
            clo = 0ull; chi = 0ull; pend = 0;
        }
    }
    {
        const long long rem = cnt - k;   // 0..3
        if (rem == 3) {
            float4 nw = pw[2 * stride], nq = pq[2 * stride];
            process(aw0, aq0); process(aw1, aq1); process(nw, nq);
        } else if (rem == 2) {
            process(aw0, aq0); process(aw1, aq1);
        } else if (rem == 1) {
            process(aw0, aq0);
        }
    }

    // scalar tail (n divisible by 4 in practice; safety only)
    for (long long t = (n4 << 2) + start; t < n; t += stride) {
        float av = w[t], bv = wq[t];
        float d = bv - av;
        sq += d * d;
        int bb = (__float_as_int(fmaf(bv, inv_a, MAGIC)) + qoff) & (NBINS - 1);
        unsigned long long one = 1ull << ((bb & 7) << 3);
        clo += (bb < 8) ? one : 0ull; chi += (bb < 8) ? 0ull : one;
        int aa = (bb << 8) + tid;
        float2 tt = sv_pl[aa]; tt.x += av; tt.y += av * av; sv_pl[aa] = tt;
    }

    // final counter flush (fields bounded well below 255: safe)
    #pragma unroll
    for (int kk = 0; kk < 8; ++kk) {
        cf[kk]     += (float)((clo >> (kk * 8)) & 0xffull);
        cf[kk + 8] += (float)((chi >> (kk * 8)) & 0xffull);
    }

    // wave-reduce sq
    for (int off = 32; off; off >>= 1) sq += __shfl_down(sq, off, 64);
    const int wave = tid >> 6, lane = tid & 63;
    if (lane == 0) sqpart[wave] = sq;

    // wave-reduce register counts into cred
    #pragma unroll
    for (int kk = 0; kk < NBINS; ++kk) {
        float v = cf[kk];
        for (int off = 32; off; off >>= 1) v += __shfl_down(v, off, 64);
        if (lane == 0) cred[kk][wave] = v;
    }
    __syncthreads();

    if (tid < NBINS)
        partial[tid * BLOCKS + blockIdx.x] =
            cred[tid][0] + cred[tid][1] + cred[tid][2] + cred[tid][3];

    // fold 256 sv columns -> 32 block partials; wave v handles cells 16+v, 20+v, ...
    for (int c = 16 + wave; c < 48; c += 4) {
        const int bin = c & 15;
        float v = 0.0f;
        if (c < 32) {
            #pragma unroll
            for (int r = 0; r < TPB / 64; ++r)
                v += sv_pl[(bin << 8) + r * 64 + lane].x;
        } else {
            #pragma unroll
            for (int r = 0; r < TPB / 64; ++r)
                v += sv_pl[(bin << 8) + r * 64 + lane].y;
        }
        for (int off = 32; off; off >>= 1) v += __shfl_down(v, off, 64);
        if (lane == 0) partial[c * BLOCKS + blockIdx.x] = v;
    }
    if (tid == 0)
        partial[48 * BLOCKS + blockIdx.x] =
            sqpart[0] + sqpart[1] + sqpart[2] + sqpart[3];
}

__global__ __launch_bounds__(TPB) void binreg_final(
    const float* __restrict__ partial, float* __restrict__ out, long long n)
{
    __shared__ float cell[49];
    const int tid = threadIdx.x, wave = tid >> 6, lane = tid & 63;

    for (int c = wave; c < 49; c += 4) {
        float v0 = 0.0f, v1 = 0.0f, v2 = 0.0f, v3 = 0.0f;
        for (int r = lane; r < BLOCKS; r += 256) {
            v0 += partial[c * BLOCKS + r];
            v1 += partial[c * BLOCKS + r + 64];
            v2 += partial[c * BLOCKS + r + 128];
            v3 += partial[c * BLOCKS + r + 192];
        }
        float v = (v0 + v1) + (v2 + v3);
        for (int off = 32; off; off >>= 1) v += __shfl_down(v, off, 64);
        if (lane == 0) cell[c] = v;
    }
    __syncthreads();

    if (tid == 0) {
        float loss = cell[48] / (float)n;   // mean squared diff
        #pragma unroll
        for (int b = 0; b < NBINS; ++b) {
            float cnt = cell[b];
            float s   = cell[16 + b];
            float ss  = cell[32 + b];
            if (cnt > 1.0f)
                loss += (ss - s * s / cnt) / (cnt - 1.0f);  // unbiased var
        }
        out[0] = 0.1f * loss;   // LMBDA
    }
}

extern "C" void kernel_launch(void* const* d_in, const int* in_sizes, int n_in,
                              void* d_out, int out_size, void* d_ws, size_t ws_size,
                              hipStream_t stream)
{
    const float* w     = (const float*)d_in[0];
    const float* wq    = (const float*)d_in[1];
    const int*   nbit  = (const int*)d_in[2];
    const float* alpha = (const float*)d_in[3];
    float* out     = (float*)d_out;
    float* partial = (float*)d_ws;   // 49*BLOCKS floats, fully overwritten; no memset
    long long n = (long long)in_sizes[0];

    binreg_main<<<BLOCKS, TPB, 0, stream>>>(w, wq, alpha, nbit, partial, n);
    binreg_final<<<1, TPB, 0, stream>>>(partial, out, n);
}